// Round 18
// baseline (241.495 us; speedup 1.0000x reference)
//
#include <hip/hip_runtime.h>

typedef short bf16x8 __attribute__((ext_vector_type(8)));
typedef float f32x4 __attribute__((ext_vector_type(4)));
typedef unsigned short u16;

#define S_LEN 4096
#define D_DIM 256
#define NROW  16384   // B*S

__device__ __forceinline__ u16 f2bf(float f) {
    union { float f; unsigned u; } v; v.f = f;
    unsigned r = v.u + 0x7FFFu + ((v.u >> 16) & 1u);
    return (u16)(r >> 16);
}
__device__ __forceinline__ float bf2f(u16 h) {
    union { unsigned u; float f; } v; v.u = ((unsigned)h) << 16; return v.f;
}

// Fragment-linear layouts (bf16):
//  Q/K/W: row-tile t (16 rows), kk (32-depth chunk): frag = t*4096 + kk*512,
//         elem(row_local, col) at ((col>>3)&3)*128 + row_local*8 + (col&7).
//         Lane l reads frag + l*8 -> row=l&15, depth=(l>>4)*8+e (A/B operand).
//  V^T:   panel p = b*64+kt64 (64 keys x 256 d): frag(dt,kk2) = p*16384+(dt*2+kk2)*512.
//  E^T:   frag(b, kc32, qt16) 32k x 16q, elem(q,k) at (k>>3)*128 + q*8 + (k&7)
//         -> lane l reads frag + l*8: row=q=l&15, depth=k=(l>>4)*8+e = A-operand.
__device__ __forceinline__ size_t fr_qk(int t, int kk) {
    return (size_t)t * 4096 + kk * 512;
}
__device__ __forceinline__ size_t fr_v(int p, int dt, int kk2) {
    return (size_t)p * 16384 + (dt * 2 + kk2) * 512;
}
__device__ __forceinline__ size_t e_base(int b, int kc, int qt) {
    return ((size_t)(b * 32768 + kc * 256 + qt)) * 512;
}

// async global->LDS, 16B/lane: lane l's 16B from g+l*8(u16) lands at lds+l*16.
__device__ __forceinline__ void gll16(const u16* g, u16* l) {
    __builtin_amdgcn_global_load_lds(
        (const __attribute__((address_space(1))) unsigned int*)g,
        (__attribute__((address_space(3))) unsigned int*)l, 16, 0, 0);
}

#define WAITV4 asm volatile("s_waitcnt vmcnt(4)" ::: "memory")
#define WAITV0 asm volatile("s_waitcnt vmcnt(0)" ::: "memory")
#define WAITLGKM0 asm volatile("s_waitcnt lgkmcnt(0)" ::: "memory")
#define MEMFENCE asm volatile("" ::: "memory")

// ---------------- Kernel W: W f32 -> bf16 fragments -----------------------
__global__ __launch_bounds__(256) void wconv(
    const float* __restrict__ Wq, const float* __restrict__ Wk,
    const float* __restrict__ Wv, u16* __restrict__ Wf)
{
    int i = blockIdx.x * 256 + threadIdx.x;
    int m = i >> 13;
    int idx = i & 8191;
    int ocol = idx >> 5;
    int d0 = (idx & 31) * 8;
    const float* s = (m == 0 ? Wq : (m == 1 ? Wk : Wv)) + ocol * 256 + d0;
    float4 v0 = *reinterpret_cast<const float4*>(s);
    float4 v1 = *reinterpret_cast<const float4*>(s + 4);
    union { ushort4 h[2]; int4 q; } t;
    t.h[0] = make_ushort4(f2bf(v0.x), f2bf(v0.y), f2bf(v0.z), f2bf(v0.w));
    t.h[1] = make_ushort4(f2bf(v1.x), f2bf(v1.y), f2bf(v1.z), f2bf(v1.w));
    size_t off = (size_t)m * 65536 + fr_qk(ocol >> 4, d0 >> 5)
               + ((d0 >> 3) & 3) * 128 + (ocol & 15) * 8;
    *reinterpret_cast<int4*>(Wf + off) = t.q;
}

// ---------------- Kernel A: QKV projection (32 rows/block) ----------------
__global__ __launch_bounds__(256) void qkv_proj(
    const float* __restrict__ x, const u16* __restrict__ Wf,
    const float* __restrict__ bq, const float* __restrict__ bk,
    const float* __restrict__ bv,
    u16* __restrict__ Qf, u16* __restrict__ Kf, u16* __restrict__ Vf)
{
    __shared__ u16 xs[32][264];
    const int tid = threadIdx.x;
    const int r0 = blockIdx.x * 32;

    #pragma unroll
    for (int i = 0; i < 8; ++i) {
        int c = i * 256 + tid;
        int row = c >> 6, c4 = c & 63;
        float4 v = reinterpret_cast<const float4*>(x + (size_t)(r0 + row) * D_DIM)[c4];
        *reinterpret_cast<ushort4*>(&xs[row][c4 * 4]) =
            make_ushort4(f2bf(v.x), f2bf(v.y), f2bf(v.z), f2bf(v.w));
    }
    __syncthreads();

    const int w = tid >> 6, l = tid & 63, lr = l & 15, lg = l >> 4;
    const int c0 = w * 64;

    bf16x8 a[2][8];
    #pragma unroll
    for (int qs = 0; qs < 2; ++qs)
        #pragma unroll
        for (int kk = 0; kk < 8; ++kk)
            a[qs][kk] = *reinterpret_cast<const bf16x8*>(&xs[qs * 16 + lr][kk * 32 + lg * 8]);

    const float* Bs[3] = {bq, bk, bv};

    #pragma unroll
    for (int m = 0; m < 3; ++m) {
        const u16* Wm = Wf + (size_t)m * 65536;
        f32x4 acc[2][4] = {};
        #pragma unroll
        for (int kk = 0; kk < 8; ++kk) {
            #pragma unroll
            for (int cf = 0; cf < 4; ++cf) {
                bf16x8 wfr = *reinterpret_cast<const bf16x8*>(
                    Wm + fr_qk(w * 4 + cf, kk) + l * 8);
                acc[0][cf] = __builtin_amdgcn_mfma_f32_16x16x32_bf16(a[0][kk], wfr, acc[0][cf], 0, 0, 0);
                acc[1][cf] = __builtin_amdgcn_mfma_f32_16x16x32_bf16(a[1][kk], wfr, acc[1][cf], 0, 0, 0);
            }
        }
        if (m < 2) {
            u16* outp = (m == 0) ? Qf : Kf;
            int t = r0 >> 4;
            #pragma unroll
            for (int qs = 0; qs < 2; ++qs) {
                #pragma unroll
                for (int cf = 0; cf < 4; ++cf) {
                    int col = c0 + cf * 16 + lr;
                    float bias = Bs[m][col];
                    size_t base = fr_qk(t + qs, col >> 5) + ((col >> 3) & 3) * 128 + (col & 7);
                    #pragma unroll
                    for (int r = 0; r < 4; ++r)
                        outp[base + (lg * 4 + r) * 8] = f2bf(acc[qs][cf][r] + bias);
                }
            }
        } else {
            int p  = (r0 >> 12) * 64 + ((r0 & 4095) >> 6);
            int kb = r0 & 63;
            #pragma unroll
            for (int qs = 0; qs < 2; ++qs) {
                #pragma unroll
                for (int cf = 0; cf < 4; ++cf) {
                    int d = c0 + cf * 16 + lr;
                    float bias = bv[d];
                    #pragma unroll
                    for (int r = 0; r < 4; ++r) {
                        int key = kb + qs * 16 + lg * 4 + r;
                        size_t off = fr_v(p, d >> 4, key >> 5)
                                   + ((key >> 3) & 3) * 128 + (d & 15) * 8 + (key & 7);
                        Vf[off] = f2bf(acc[qs][cf][r] + bias);
                    }
                }
            }
        }
    }
}

// ---------------- Kernel B: E^T = exp(S^T/16) + Z partials ----------------
// acc rows = k (kreg is A operand), cols = q -> lane holds 4 consecutive k;
// E^T fragments written with coalesced ushort4 stores (write_e=1).
__global__ __launch_bounds__(256, 2) void score_exp(
    const u16* __restrict__ Qf, const u16* __restrict__ Kf,
    u16* __restrict__ Ef, float* __restrict__ Zp, int write_e)
{
    __shared__ __align__(16) u16 Qls[2][8192];    // 2 x 16KB (32-q panels)
    const int tid = threadIdx.x, blk = blockIdx.x;
    const int xcd = blk & 7, sub = blk >> 3;      // sub 0..63
    const int b  = xcd >> 1;
    const int qq = ((xcd & 1) << 1) | (sub & 1);  // q-quarter 0..3
    const int ktile = sub >> 1;                   // 0..31 (128 keys)
    const int w = tid >> 6, l = tid & 63, lr = l & 15, lg = l >> 4;
    const int k0 = ktile * 128;

    bf16x8 kreg[2][8];
    #pragma unroll
    for (int ks = 0; ks < 2; ++ks) {
        const int tk = b * 256 + (k0 >> 4) + w * 2 + ks;
        #pragma unroll
        for (int kk = 0; kk < 8; ++kk)
            kreg[ks][kk] = *reinterpret_cast<const bf16x8*>(Kf + fr_qk(tk, kk) + l * 8);
    }

    #define STAGE_Q(qt_, nb_) do { \
        const u16* g_ = Qf + ((size_t)(b * 256 + (qt_) * 2)) * 4096 + (w * 4) * 512 + l * 8; \
        u16* d_ = &Qls[nb_][(w * 4) * 512]; \
        _Pragma("unroll") \
        for (int f_ = 0; f_ < 4; ++f_) gll16(g_ + f_ * 512, d_ + f_ * 512); \
    } while (0)

    const int qt0 = qq * 32;
    STAGE_Q(qt0, 0);
    __syncthreads();

    float Z[2][4] = {};
    const float SC = 0.0625f;
    const int kc = ktile * 4 + w;                 // this wave's 32-key chunk

    for (int it = 0; it < 32; ++it) {
        const int cur = it & 1;
        if (it < 31) STAGE_Q(qt0 + it + 1, cur ^ 1);

        f32x4 acc[2][2] = {};
        #pragma unroll
        for (int kk = 0; kk < 8; ++kk) {
            #pragma unroll
            for (int qf = 0; qf < 2; ++qf) {
                bf16x8 qfr = *reinterpret_cast<const bf16x8*>(
                    &Qls[cur][(qf * 8 + kk) * 512 + l * 8]);
                acc[0][qf] = __builtin_amdgcn_mfma_f32_16x16x32_bf16(kreg[0][kk], qfr, acc[0][qf], 0, 0, 0);
                acc[1][qf] = __builtin_amdgcn_mfma_f32_16x16x32_bf16(kreg[1][kk], qfr, acc[1][qf], 0, 0, 0);
            }
        }
        #pragma unroll
        for (int ks = 0; ks < 2; ++ks) {
            #pragma unroll
            for (int qf = 0; qf < 2; ++qf) {
                float e0 = __expf(acc[ks][qf][0] * SC);
                float e1 = __expf(acc[ks][qf][1] * SC);
                float e2 = __expf(acc[ks][qf][2] * SC);
                float e3 = __expf(acc[ks][qf][3] * SC);
                Z[ks][0] += e0; Z[ks][1] += e1; Z[ks][2] += e2; Z[ks][3] += e3;
                if (write_e) {
                    size_t ad = e_base(b, kc, (qt0 + it) * 2 + qf)
                              + (ks * 2 + (lg >> 1)) * 128 + lr * 8 + (lg & 1) * 4;
                    *reinterpret_cast<ushort4*>(Ef + ad) =
                        make_ushort4(f2bf(e0), f2bf(e1), f2bf(e2), f2bf(e3));
                }
            }
        }
        __syncthreads();
    }

    #pragma unroll
    for (int ks = 0; ks < 2; ++ks) {
        #pragma unroll
        for (int r = 0; r < 4; ++r) {
            float z = Z[ks][r];
            z += __shfl_xor(z, 1);
            z += __shfl_xor(z, 2);
            z += __shfl_xor(z, 4);
            z += __shfl_xor(z, 8);
            if (lr == 0)
                Zp[qq * NROW + b * S_LEN + k0 + w * 32 + ks * 16 + lg * 4 + r] = z;
        }
    }
    #undef STAGE_Q
}

// ---------------- Kernel Z: rZ = 1 / sum(4 partials) (fixed order) --------
__global__ __launch_bounds__(256) void zrecip(
    const float* __restrict__ Zp, float* __restrict__ rZ)
{
    int i = blockIdx.x * 256 + threadIdx.x;
    rZ[i] = 1.0f / (((Zp[i] + Zp[NROW + i]) + Zp[2 * NROW + i]) + Zp[3 * NROW + i]);
}

// ---------------- Kernel Z2: LZ = log(sum of 4 partials) (fallback) -------
__global__ __launch_bounds__(256) void zlog(
    const float* __restrict__ Zp, float* __restrict__ LZ)
{
    int i = blockIdx.x * 256 + threadIdx.x;
    LZ[i] = logf(((Zp[i] + Zp[NROW + i]) + Zp[2 * NROW + i]) + Zp[3 * NROW + i]);
}

// ---------------- Kernel V: V' = rZ[k] * V (in place on Vf) ---------------
__global__ __launch_bounds__(256) void vscale(
    u16* __restrict__ Vf, const float* __restrict__ rZ)
{
    int i = blockIdx.x * 256 + threadIdx.x;       // 524288 threads, 8 u16 each
    int frag = i >> 6, l8 = i & 63;
    int p = frag >> 5, sub = frag & 31, kk2 = sub & 1;
    int b = p >> 6, kt = p & 63;
    int kbase = b * S_LEN + kt * 64 + kk2 * 32 + (l8 >> 4) * 8;
    float4 rz0 = *reinterpret_cast<const float4*>(&rZ[kbase]);
    float4 rz1 = *reinterpret_cast<const float4*>(&rZ[kbase + 4]);
    ushort4* vp = reinterpret_cast<ushort4*>(Vf + (size_t)i * 8);
    ushort4 a = vp[0], c = vp[1];
    vp[0] = make_ushort4(f2bf(bf2f(a.x) * rz0.x), f2bf(bf2f(a.y) * rz0.y),
                         f2bf(bf2f(a.z) * rz0.z), f2bf(bf2f(a.w) * rz0.w));
    vp[1] = make_ushort4(f2bf(bf2f(c.x) * rz1.x), f2bf(bf2f(c.y) * rz1.y),
                         f2bf(bf2f(c.z) * rz1.z), f2bf(bf2f(c.w) * rz1.w));
}

// ---------------- Kernel C: out = E^T' @ V' (64q x 64d waves) -------------
// LDS-port relief: wave = 4 E frags (regs) x 4 V frags (LDS) -> 16 MFMAs
// per 4KB of LDS reads (r17: 16 MFMAs per 8KB). Block = 128q x 128d
// (2qh x 2dh waves), k-split-8 -> grid 2048, 16 iters of 32k. E keeps the
// r17 order-pinned depth-1 rotation (eA/eB/eC); FIFO per iter:
// [E(it+1) x4] [V(it+1) x2] [E(it+2) x4] -> WAITV4 retires E(it+1)+V(it+1),
// leaves E(it+2) in flight across the barrier. Tails peeled unconditionally.
__global__ __launch_bounds__(256, 4) void pv_gemm(
    const u16* __restrict__ Ef, const u16* __restrict__ Vf, float* __restrict__ out)
{
    __shared__ __align__(16) u16 Vls[2][4096];    // 2 x 8KB (8 V frags: 32k x 128d)

    const int tid = threadIdx.x, blk = blockIdx.x;
    const int xcd = blk & 7, sub = blk >> 3;      // sub 0..255
    const int b   = xcd >> 1;
    const int kq  = ((xcd & 1) << 2) | (sub & 3); // key-eighth 0..7
    const int rem = sub >> 2;                     // 0..63
    const int qt  = rem >> 1;                     // q-tile 0..31 (128 q rows)
    const int dh2 = rem & 1;                      // block d-half (128 d)
    const int w = tid >> 6, l = tid & 63, lr = l & 15, lg = l >> 4;
    const int qh = w & 1, dh = w >> 1;            // wave: 64q half x 64d quarter

    #define EADDR(it_, j_) \
        (Ef + e_base(b, kq * 16 + (it_), qt * 8 + qh * 4 + (j_)) + l * 8)

    // stage the 8 V frags (global dt = dh2*8 + f) of k-chunk it_; wave does 2
    #define STAGE_V(it_, nb_) do { \
        const int kc_ = kq * 16 + (it_); \
        const size_t vb_ = ((size_t)(b * 64 + (kc_ >> 1))) * 16384 + (kc_ & 1) * 512; \
        _Pragma("unroll") \
        for (int f_ = 0; f_ < 2; ++f_) { \
            int fl_ = w * 2 + f_; \
            gll16(Vf + vb_ + (size_t)((dh2 * 8 + fl_) * 1024) + l * 8, &Vls[nb_][fl_ * 512]); \
        } \
    } while (0)

    #define LOADE(it_, e0_, e1_, e2_, e3_) do { \
        e0_ = *reinterpret_cast<const bf16x8*>(EADDR(it_, 0)); \
        e1_ = *reinterpret_cast<const bf16x8*>(EADDR(it_, 1)); \
        e2_ = *reinterpret_cast<const bf16x8*>(EADDR(it_, 2)); \
        e3_ = *reinterpret_cast<const bf16x8*>(EADDR(it_, 3)); \
    } while (0)

    #define COMPUTE(nb_, e0_, e1_, e2_, e3_) do { \
        __builtin_amdgcn_s_setprio(1); \
        _Pragma("unroll") \
        for (int df = 0; df < 4; ++df) { \
            bf16x8 vfr = *reinterpret_cast<const bf16x8*>( \
                &Vls[nb_][(dh * 4 + df) * 512 + l * 8]); \
            acc[0][df] = __builtin_amdgcn_mfma_f32_16x16x32_bf16(e0_, vfr, acc[0][df], 0, 0, 0); \
            acc[1][df] = __builtin_amdgcn_mfma_f32_16x16x32_bf16(e1_, vfr, acc[1][df], 0, 0, 0); \
            acc[2][df] = __builtin_amdgcn_mfma_f32_16x16x32_bf16(e2_, vfr, acc[2][df], 0, 0, 0); \
            acc[3][df] = __builtin_amdgcn_mfma_f32_16x16x32_bf16(e3_, vfr, acc[3][df], 0, 0, 0); \
        } \
        __builtin_amdgcn_s_setprio(0); \
    } while (0)

    // body: stage V(it+1) [fence] load E(it+2)->eN [fence] compute(it, eC),
    // WAITV4 leaves exactly E(it+2) in flight across the barrier.
    #define BODY(it_, C0,C1,C2,C3, N0,N1,N2,N3) do { \
        STAGE_V((it_) + 1, ((it_) + 1) & 1); \
        MEMFENCE; \
        LOADE((it_) + 2, N0, N1, N2, N3); \
        MEMFENCE; \
        COMPUTE((it_) & 1, C0, C1, C2, C3); \
        WAITV4; \
        __builtin_amdgcn_s_barrier(); \
        MEMFENCE; \
    } while (0)

    f32x4 acc[4][4] = {};
    bf16x8 eA0, eA1, eA2, eA3, eB0, eB1, eB2, eB3, eC0, eC1, eC2, eC3;

    // prologue: eA=E(0) [fence] V(0)->buf0 [fence] eB=E(1);
    // WAITV4 retires eA+V(0) (order pinned), leaves eB's 4 loads in flight.
    LOADE(0, eA0, eA1, eA2, eA3);
    MEMFENCE;
    STAGE_V(0, 0);
    MEMFENCE;
    LOADE(1, eB0, eB1, eB2, eB3);
    MEMFENCE;
    WAITV4;
    __builtin_amdgcn_s_barrier();
    MEMFENCE;

    #pragma unroll 1
    for (int base = 0; base < 12; base += 3) {
        BODY(base,     eA0,eA1,eA2,eA3, eC0,eC1,eC2,eC3);  // compute E(it),   load E(it+2)->eC
        BODY(base + 1, eB0,eB1,eB2,eB3, eA0,eA1,eA2,eA3);  // compute E(it+1), load E(it+3)->eA
        BODY(base + 2, eC0,eC1,eC2,eC3, eB0,eB1,eB2,eB3);  // compute E(it+2), load E(it+4)->eB
    }
    // it = 12 (eA holds E(12), eB holds E(13) in flight)
    STAGE_V(13, 1);
    MEMFENCE;
    LOADE(14, eC0, eC1, eC2, eC3);
    MEMFENCE;
    COMPUTE(0, eA0, eA1, eA2, eA3);
    WAITV4;
    __builtin_amdgcn_s_barrier();
    MEMFENCE;
    // it = 13
    STAGE_V(14, 0);
    MEMFENCE;
    LOADE(15, eA0, eA1, eA2, eA3);
    MEMFENCE;
    COMPUTE(1, eB0, eB1, eB2, eB3);
    WAITV4;
    __builtin_amdgcn_s_barrier();
    MEMFENCE;
    // it = 14: stage V(15), compute eC, full drain (V(15)+E(15))
    STAGE_V(15, 1);
    MEMFENCE;
    COMPUTE(0, eC0, eC1, eC2, eC3);
    WAITV0;
    __builtin_amdgcn_s_barrier();
    MEMFENCE;
    // it = 15
    COMPUTE(1, eA0, eA1, eA2, eA3);

    // epilogue: C rows = q (lg*4+r), cols = d (lr); 8 contributions/element
    const int qg = b * S_LEN + qt * 128 + qh * 64;
    const int dg = dh2 * 128 + dh * 64;
    #pragma unroll
    for (int qf = 0; qf < 4; ++qf) {
        #pragma unroll
        for (int df = 0; df < 4; ++df) {
            #pragma unroll
            for (int r = 0; r < 4; ++r) {
                unsafeAtomicAdd(&out[(size_t)(qg + qf * 16 + lg * 4 + r) * D_DIM
                                     + dg + df * 16 + lr],
                                acc[qf][df][r]);
            }
        }
    }
    #undef EADDR
    #undef STAGE_V
    #undef LOADE
    #undef COMPUTE
    #undef BODY
}

// ================= FALLBACK (round-11 fused attn_out) =====================
__global__ __launch_bounds__(512, 1) void attn_out_fb(
    const u16* __restrict__ Qf, const u16* __restrict__ Kf, const u16* __restrict__ Vf,
    const float* __restrict__ LZ, float* __restrict__ out)
{
    __shared__ __align__(16) u16 Kls[3][8192];
    __shared__ __align__(16) u16 Vls[4][8192];
    __shared__ __align__(16) u16 ps[8][2][1280];
    __shared__ __align__(16) float lzs[1024];

    const int tid = threadIdx.x, blk = blockIdx.x;
    const int xcd = blk & 7, sub = blk >> 3;
    const int b  = xcd >> 1;
    const int kq = ((xcd & 1) << 1) | (sub & 1);
    const int qtile = sub >> 1;
    const int w = tid >> 6, l = tid & 63, lr = l & 15, lg = l >> 4;
    const int q0 = qtile * 256 + w * 32;
    const int base_tk = b * 256;
    const int kt0 = kq * 32;

    bf16x8 qreg[2][8];
    #pragma unroll
    for (int qs = 0; qs < 2; ++qs) {
        const int tq = base_tk + ((q0 + qs * 16) >> 4);
        #pragma unroll
        for (int kk = 0; kk < 8; ++kk)
            qreg[qs][kk] = *reinterpret_cast<const bf16x8*>(Qf + fr_qk(tq, kk) + l * 8);
    }

    #define STAGE(kt_) do { \
        if (w < 4) { \
            const u16* g_ = Kf + ((size_t)(base_tk + (kt0 + (kt_)) * 2)) * 4096 + (w * 4) * 512 + l * 8; \
            u16* d_ = &Kls[(kt_) % 3][(w * 4) * 512]; \
            _Pragma("unroll") \
            for (int f_ = 0; f_ < 4; ++f_) gll16(g_ + f_ * 512, d_ + f_ * 512); \
        } else { \
            const int kta_ = kt0 + (kt_); \
            const size_t vb_ = ((size_t)(b * 64 + (kta_ >> 1))) * 16384 + (kta_ & 1) * 512; \
            const int dt0_ = (w - 4) * 4; \
            _Pragma("unroll") \
            for (int f_ = 0; f_ < 4; ++f_) \
                gll16(Vf + vb_ + (size_t)(dt0_ + f_) * 1024 + l * 8, &Vls[(kt_) % 4][(dt0_ + f_) * 512]); \
        } \
    } while (0)

    #define QK(kt_) do { \
        const u16* kb_ = &Kls[(kt_) % 3][0]; \
        __builtin_amdgcn_s_setprio(1); \
        _Pragma("unroll") \
        for (int kk = 0; kk < 8; ++kk) { \
            bf16x8 k0_ = *reinterpret_cast<const bf16x8*>(kb_ + kk * 512 + l * 8); \
            bf16x8 k1_ = *reinterpret_cast<const bf16x8*>(kb_ + (8 + kk) * 512 + l * 8); \
            sacc[0][0] = __builtin_amdgcn_mfma_f32_16x16x32_bf16(qreg[0][kk], k0_, sacc[0][0], 0, 0, 0); \
            sacc[0][1] = __builtin_amdgcn_mfma_f32_16x16x32_bf16(qreg[1][kk], k0_, sacc[0][1], 0, 0, 0); \
            sacc[1][0] = __builtin_amdgcn_mfma_f32_16x16x32_bf16(qreg[0][kk], k1_, sacc[1][0], 0, 0, 0); \
            sacc[1][1] = __builtin_amdgcn_mfma_f32_16x16x32_bf16(qreg[1][kk], k1_, sacc[1][1], 0, 0, 0); \
        } \
        __builtin_amdgcn_s_setprio(0); \
    } while (0)

    #define PV(j_) do { \
        const u16* vb_ = &Vls[(j_) % 4][0]; \
        const u16* pb_ = &ps[w][(j_) & 1][0]; \
        bf16x8 af0_ = *reinterpret_cast<const bf16x8*>(pb_ + lr * 40 + lg * 8); \
        bf16x8 af1_ = *reinterpret_cast<const bf16x8*>(pb_ + (16 + lr) * 40 + lg * 8); \
        __builtin_amdgcn_s_setprio(1); \
        _Pragma("unroll") \
        for (int dt = 0; dt < 16; ++dt) { \
            bf16x8 vf_ = *reinterpret_cast<const bf16x8*>(vb_ + dt * 512 + l * 8); \
            oacc[0][dt] = __builtin_amdgcn_mfma_f32_16x16x32_bf16(af0_, vf_, oacc[0][dt], 0, 0, 0); \
            oacc[1][dt] = __builtin_amdgcn_mfma_f32_16x16x32_bf16(af1_, vf_, oacc[1][dt], 0, 0, 0); \
        } \
        __builtin_amdgcn_s_setprio(0); \
    } while (0)

    #define SM(kt_) do { \
        u16* pw_ = &ps[w][(kt_) & 1][0]; \
        _Pragma("unroll") \
        for (int cf = 0; cf < 2; ++cf) { \
            float Lv_ = lzs[(kt_) * 32 + cf * 16 + lr]; \
            _Pragma("unroll") \
            for (int qs = 0; qs < 2; ++qs) \
                _Pragma("unroll") \
                for (int r = 0; r < 4; ++r) { \
                    float p_ = __expf(fmaf(sacc[cf][qs][r], SC, -Lv_)); \
                    pw_[(qs * 16 + lg * 4 + r) * 40 + cf * 16 + lr] = f2bf(p_); \
                } \
        } \
    } while (0)

    f32x4 oacc[2][16] = {};
    const float SC = 0.0625f;

    f32x4 lzv;
    if (tid < 256)
        lzv = *reinterpret_cast<const f32x4*>(LZ + b * S_LEN + kt0 * 32 + tid * 4);
    STAGE(0);
    STAGE(1);
    if (tid < 256)
        *reinterpret_cast<f32x4*>(&lzs[tid * 4]) = lzv;
    WAITLGKM0;
    WAITV4;
    __builtin_amdgcn_s_barrier();
    MEMFENCE;

    #pragma unroll 1
    for (int kt = 0; kt < 30; ++kt) {
        STAGE(kt + 2);
        f32x4 sacc[2][2] = {};
        QK(kt);
        if (kt > 0) PV(kt - 1);
        SM(kt);
        WAITV4;
        __builtin_amdgcn_s_barrier();
        MEMFENCE;
    }
    {
        f32x4 sacc[2][2] = {};
        QK(30); PV(29); SM(30);
        WAITV0;
        __builtin_amdgcn_s_barrier();
        MEMFENCE;
    }
    {
        f32x4 sacc[2][2] = {};
        QK(31); PV(30); SM(31); PV(31);
    }

    #pragma unroll
    for (int qs = 0; qs < 2; ++qs) {
        #pragma unroll
        for (int dt = 0; dt < 16; ++dt) {
            #pragma unroll
            for (int r = 0; r < 4; ++r) {
                int row = q0 + qs * 16 + lg * 4 + r;
                unsafeAtomicAdd(&out[((size_t)(b * S_LEN + row)) * D_DIM + dt * 16 + lr],
                                oacc[qs][dt][r]);
            }
        }
    }
    #undef STAGE
    #undef QK
    #undef PV
    #undef SM
}

// ---------------- launcher ------------------------------------------------
extern "C" void kernel_launch(void* const* d_in, const int* in_sizes, int n_in,
                              void* d_out, int out_size, void* d_ws, size_t ws_size,
                              hipStream_t stream) {
    const float* x  = (const float*)d_in[0];
    const float* Wq = (const float*)d_in[1];
    const float* bq = (const float*)d_in[2];
    const float* Wk = (const float*)d_in[3];
    const float* bk = (const float*)d_in[4];
    const float* Wv = (const float*)d_in[5];
    const float* bv = (const float*)d_in[6];
    float* out = (float*)d_out;

    u16* Qf = (u16*)d_ws;                              // 8 MB (fragment layout)
    u16* Kf = Qf + (size_t)NROW * D_DIM;               // 8 MB
    u16* Vf = Kf + (size_t)NROW * D_DIM;               // 8 MB
    u16* Wf = Vf + (size_t)NROW * D_DIM;               // 384 KB
    float* Zp = (float*)(Wf + 196608);                 // 256 KB (4 q-quarter partials)
    float* rZ = Zp + 4 * NROW;                         // 64 KB (rZ or LZ)
    u16* Ef = (u16*)(rZ + NROW);                       // 134.2 MB

    const size_t need = (size_t)((char*)Ef - (char*)d_ws) + (size_t)4 * 32768 * 512 * 2;

    hipMemsetAsync(out, 0, (size_t)NROW * D_DIM * sizeof(float), stream);
    wconv<<<96, 256, 0, stream>>>(Wq, Wk, Wv, Wf);
    qkv_proj<<<NROW / 32, 256, 0, stream>>>(x, Wf, bq, bk, bv, Qf, Kf, Vf);

    if (ws_size >= need) {
        score_exp<<<512, 256, 0, stream>>>(Qf, Kf, Ef, Zp, 1);
        zrecip<<<NROW / 256, 256, 0, stream>>>(Zp, rZ);
        vscale<<<2048, 256, 0, stream>>>(Vf, rZ);
        pv_gemm<<<2048, 256, 0, stream>>>(Ef, Vf, out);
    } else {
        score_exp<<<512, 256, 0, stream>>>(Qf, Kf, Qf /*unused*/, Zp, 0);
        zlog<<<NROW / 256, 256, 0, stream>>>(Zp, rZ);
        attn_out_fb<<<256, 512, 0, stream>>>(Qf, Kf, Vf, rZ, out);
    }
}

// Round 19
// 161.399 us; speedup vs baseline: 1.4963x; 1.4963x over previous
//
#include <hip/hip_runtime.h>

typedef short bf16x8 __attribute__((ext_vector_type(8)));
typedef float f32x4 __attribute__((ext_vector_type(4)));
typedef unsigned short u16;

#define S_LEN 4096
#define D_DIM 256
#define NROW  16384   // B*S

__device__ __forceinline__ u16 f2bf(float f) {
    union { float f; unsigned u; } v; v.f = f;
    unsigned r = v.u + 0x7FFFu + ((v.u >> 16) & 1u);
    return (u16)(r >> 16);
}
__device__ __forceinline__ float bf2f(u16 h) {
    union { unsigned u; float f; } v; v.u = ((unsigned)h) << 16; return v.f;
}

// Fragment-linear layouts (bf16):
//  Q/K/W: row-tile t (16 rows), kk (32-depth chunk): frag = t*4096 + kk*512,
//         elem(row_local, col) at ((col>>3)&3)*128 + row_local*8 + (col&7).
//         Lane l reads frag + l*8 -> row=l&15, depth=(l>>4)*8+e (A/B operand).
//  V^T:   panel p = b*64+kt64 (64 keys x 256 d): frag(dt,kk2) = p*16384+(dt*2+kk2)*512.
//  E^T:   frag(b, kc32, qt16) 32k x 16q, elem(q,k) at (k>>3)*128 + q*8 + (k&7)
//         -> lane l reads frag + l*8: row=q=l&15, depth=k=(l>>4)*8+e = A-operand.
__device__ __forceinline__ size_t fr_qk(int t, int kk) {
    return (size_t)t * 4096 + kk * 512;
}
__device__ __forceinline__ size_t fr_v(int p, int dt, int kk2) {
    return (size_t)p * 16384 + (dt * 2 + kk2) * 512;
}
__device__ __forceinline__ size_t e_base(int b, int kc, int qt) {
    return ((size_t)(b * 32768 + kc * 256 + qt)) * 512;
}

// async global->LDS, 16B/lane: lane l's 16B from g+l*8(u16) lands at lds+l*16.
__device__ __forceinline__ void gll16(const u16* g, u16* l) {
    __builtin_amdgcn_global_load_lds(
        (const __attribute__((address_space(1))) unsigned int*)g,
        (__attribute__((address_space(3))) unsigned int*)l, 16, 0, 0);
}

#define WAITV4 asm volatile("s_waitcnt vmcnt(4)" ::: "memory")
#define WAITV2 asm volatile("s_waitcnt vmcnt(2)" ::: "memory")
#define WAITV0 asm volatile("s_waitcnt vmcnt(0)" ::: "memory")
#define WAITLGKM0 asm volatile("s_waitcnt lgkmcnt(0)" ::: "memory")
#define MEMFENCE asm volatile("" ::: "memory")

// ---------------- Kernel W: W f32 -> bf16 fragments -----------------------
__global__ __launch_bounds__(256) void wconv(
    const float* __restrict__ Wq, const float* __restrict__ Wk,
    const float* __restrict__ Wv, u16* __restrict__ Wf)
{
    int i = blockIdx.x * 256 + threadIdx.x;
    int m = i >> 13;
    int idx = i & 8191;
    int ocol = idx >> 5;
    int d0 = (idx & 31) * 8;
    const float* s = (m == 0 ? Wq : (m == 1 ? Wk : Wv)) + ocol * 256 + d0;
    float4 v0 = *reinterpret_cast<const float4*>(s);
    float4 v1 = *reinterpret_cast<const float4*>(s + 4);
    union { ushort4 h[2]; int4 q; } t;
    t.h[0] = make_ushort4(f2bf(v0.x), f2bf(v0.y), f2bf(v0.z), f2bf(v0.w));
    t.h[1] = make_ushort4(f2bf(v1.x), f2bf(v1.y), f2bf(v1.z), f2bf(v1.w));
    size_t off = (size_t)m * 65536 + fr_qk(ocol >> 4, d0 >> 5)
               + ((d0 >> 3) & 3) * 128 + (ocol & 15) * 8;
    *reinterpret_cast<int4*>(Wf + off) = t.q;
}

// ---------------- Kernel A: QKV projection (32 rows/block) ----------------
__global__ __launch_bounds__(256) void qkv_proj(
    const float* __restrict__ x, const u16* __restrict__ Wf,
    const float* __restrict__ bq, const float* __restrict__ bk,
    const float* __restrict__ bv,
    u16* __restrict__ Qf, u16* __restrict__ Kf, u16* __restrict__ Vf)
{
    __shared__ u16 xs[32][264];
    const int tid = threadIdx.x;
    const int r0 = blockIdx.x * 32;

    #pragma unroll
    for (int i = 0; i < 8; ++i) {
        int c = i * 256 + tid;
        int row = c >> 6, c4 = c & 63;
        float4 v = reinterpret_cast<const float4*>(x + (size_t)(r0 + row) * D_DIM)[c4];
        *reinterpret_cast<ushort4*>(&xs[row][c4 * 4]) =
            make_ushort4(f2bf(v.x), f2bf(v.y), f2bf(v.z), f2bf(v.w));
    }
    __syncthreads();

    const int w = tid >> 6, l = tid & 63, lr = l & 15, lg = l >> 4;
    const int c0 = w * 64;

    bf16x8 a[2][8];
    #pragma unroll
    for (int qs = 0; qs < 2; ++qs)
        #pragma unroll
        for (int kk = 0; kk < 8; ++kk)
            a[qs][kk] = *reinterpret_cast<const bf16x8*>(&xs[qs * 16 + lr][kk * 32 + lg * 8]);

    const float* Bs[3] = {bq, bk, bv};

    #pragma unroll
    for (int m = 0; m < 3; ++m) {
        const u16* Wm = Wf + (size_t)m * 65536;
        f32x4 acc[2][4] = {};
        #pragma unroll
        for (int kk = 0; kk < 8; ++kk) {
            #pragma unroll
            for (int cf = 0; cf < 4; ++cf) {
                bf16x8 wfr = *reinterpret_cast<const bf16x8*>(
                    Wm + fr_qk(w * 4 + cf, kk) + l * 8);
                acc[0][cf] = __builtin_amdgcn_mfma_f32_16x16x32_bf16(a[0][kk], wfr, acc[0][cf], 0, 0, 0);
                acc[1][cf] = __builtin_amdgcn_mfma_f32_16x16x32_bf16(a[1][kk], wfr, acc[1][cf], 0, 0, 0);
            }
        }
        if (m < 2) {
            u16* outp = (m == 0) ? Qf : Kf;
            int t = r0 >> 4;
            #pragma unroll
            for (int qs = 0; qs < 2; ++qs) {
                #pragma unroll
                for (int cf = 0; cf < 4; ++cf) {
                    int col = c0 + cf * 16 + lr;
                    float bias = Bs[m][col];
                    size_t base = fr_qk(t + qs, col >> 5) + ((col >> 3) & 3) * 128 + (col & 7);
                    #pragma unroll
                    for (int r = 0; r < 4; ++r)
                        outp[base + (lg * 4 + r) * 8] = f2bf(acc[qs][cf][r] + bias);
                }
            }
        } else {
            int p  = (r0 >> 12) * 64 + ((r0 & 4095) >> 6);
            int kb = r0 & 63;
            #pragma unroll
            for (int qs = 0; qs < 2; ++qs) {
                #pragma unroll
                for (int cf = 0; cf < 4; ++cf) {
                    int d = c0 + cf * 16 + lr;
                    float bias = bv[d];
                    #pragma unroll
                    for (int r = 0; r < 4; ++r) {
                        int key = kb + qs * 16 + lg * 4 + r;
                        size_t off = fr_v(p, d >> 4, key >> 5)
                                   + ((key >> 3) & 3) * 128 + (d & 15) * 8 + (key & 7);
                        Vf[off] = f2bf(acc[qs][cf][r] + bias);
                    }
                }
            }
        }
    }
}

// ---------------- Kernel B: E^T = exp(S^T/16) + Z partials ----------------
// q-split-8 (grid 1024 -> 4 blocks/CU, the r18 lever). Block = (b, 128-key
// tile, q-eighth): 16 iters of 32-q panels. acc rows = k (kreg A operand);
// E^T fragments written with coalesced ushort4 stores (write_e=1).
// Zp: 8 fixed-order partials.
__global__ __launch_bounds__(256, 4) void score_exp(
    const u16* __restrict__ Qf, const u16* __restrict__ Kf,
    u16* __restrict__ Ef, float* __restrict__ Zp, int write_e)
{
    __shared__ __align__(16) u16 Qls[2][8192];    // 2 x 16KB (32-q panels)
    const int tid = threadIdx.x, blk = blockIdx.x;
    const int xcd = blk & 7, sub = blk >> 3;      // sub 0..127
    const int b  = xcd >> 1;
    const int qe = ((xcd & 1) << 2) | (sub & 3);  // q-eighth 0..7
    const int ktile = sub >> 2;                   // 0..31 (128 keys)
    const int w = tid >> 6, l = tid & 63, lr = l & 15, lg = l >> 4;
    const int k0 = ktile * 128;

    bf16x8 kreg[2][8];
    #pragma unroll
    for (int ks = 0; ks < 2; ++ks) {
        const int tk = b * 256 + (k0 >> 4) + w * 2 + ks;
        #pragma unroll
        for (int kk = 0; kk < 8; ++kk)
            kreg[ks][kk] = *reinterpret_cast<const bf16x8*>(Kf + fr_qk(tk, kk) + l * 8);
    }

    #define STAGE_Q(qt_, nb_) do { \
        const u16* g_ = Qf + ((size_t)(b * 256 + (qt_) * 2)) * 4096 + (w * 4) * 512 + l * 8; \
        u16* d_ = &Qls[nb_][(w * 4) * 512]; \
        _Pragma("unroll") \
        for (int f_ = 0; f_ < 4; ++f_) gll16(g_ + f_ * 512, d_ + f_ * 512); \
    } while (0)

    const int qt0 = qe * 16;                      // 16 panels of 32 q
    STAGE_Q(qt0, 0);
    __syncthreads();

    float Z[2][4] = {};
    const float SC = 0.0625f;
    const int kc = ktile * 4 + w;                 // this wave's 32-key chunk

    for (int it = 0; it < 16; ++it) {
        const int cur = it & 1;
        if (it < 15) STAGE_Q(qt0 + it + 1, cur ^ 1);

        f32x4 acc[2][2] = {};
        #pragma unroll
        for (int kk = 0; kk < 8; ++kk) {
            #pragma unroll
            for (int qf = 0; qf < 2; ++qf) {
                bf16x8 qfr = *reinterpret_cast<const bf16x8*>(
                    &Qls[cur][(qf * 8 + kk) * 512 + l * 8]);
                acc[0][qf] = __builtin_amdgcn_mfma_f32_16x16x32_bf16(kreg[0][kk], qfr, acc[0][qf], 0, 0, 0);
                acc[1][qf] = __builtin_amdgcn_mfma_f32_16x16x32_bf16(kreg[1][kk], qfr, acc[1][qf], 0, 0, 0);
            }
        }
        #pragma unroll
        for (int ks = 0; ks < 2; ++ks) {
            #pragma unroll
            for (int qf = 0; qf < 2; ++qf) {
                float e0 = __expf(acc[ks][qf][0] * SC);
                float e1 = __expf(acc[ks][qf][1] * SC);
                float e2 = __expf(acc[ks][qf][2] * SC);
                float e3 = __expf(acc[ks][qf][3] * SC);
                Z[ks][0] += e0; Z[ks][1] += e1; Z[ks][2] += e2; Z[ks][3] += e3;
                if (write_e) {
                    size_t ad = e_base(b, kc, (qt0 + it) * 2 + qf)
                              + (ks * 2 + (lg >> 1)) * 128 + lr * 8 + (lg & 1) * 4;
                    *reinterpret_cast<ushort4*>(Ef + ad) =
                        make_ushort4(f2bf(e0), f2bf(e1), f2bf(e2), f2bf(e3));
                }
            }
        }
        __syncthreads();
    }

    #pragma unroll
    for (int ks = 0; ks < 2; ++ks) {
        #pragma unroll
        for (int r = 0; r < 4; ++r) {
            float z = Z[ks][r];
            z += __shfl_xor(z, 1);
            z += __shfl_xor(z, 2);
            z += __shfl_xor(z, 4);
            z += __shfl_xor(z, 8);
            if (lr == 0)
                Zp[qe * NROW + b * S_LEN + k0 + w * 32 + ks * 16 + lg * 4 + r] = z;
        }
    }
    #undef STAGE_Q
}

// ---------------- Kernel Z: rZ = 1 / sum(8 partials) (fixed order) --------
__global__ __launch_bounds__(256) void zrecip(
    const float* __restrict__ Zp, float* __restrict__ rZ)
{
    int i = blockIdx.x * 256 + threadIdx.x;
    float s = Zp[i];
    #pragma unroll
    for (int p = 1; p < 8; ++p) s += Zp[p * NROW + i];
    rZ[i] = 1.0f / s;
}

// ---------------- Kernel Z2: LZ = log(sum of 8 partials) (fallback) -------
__global__ __launch_bounds__(256) void zlog(
    const float* __restrict__ Zp, float* __restrict__ LZ)
{
    int i = blockIdx.x * 256 + threadIdx.x;
    float s = Zp[i];
    #pragma unroll
    for (int p = 1; p < 8; ++p) s += Zp[p * NROW + i];
    LZ[i] = logf(s);
}

// ---------------- Kernel V: V' = rZ[k] * V (in place on Vf) ---------------
__global__ __launch_bounds__(256) void vscale(
    u16* __restrict__ Vf, const float* __restrict__ rZ)
{
    int i = blockIdx.x * 256 + threadIdx.x;       // 524288 threads, 8 u16 each
    int frag = i >> 6, l8 = i & 63;
    int p = frag >> 5, sub = frag & 31, kk2 = sub & 1;
    int b = p >> 6, kt = p & 63;
    int kbase = b * S_LEN + kt * 64 + kk2 * 32 + (l8 >> 4) * 8;
    float4 rz0 = *reinterpret_cast<const float4*>(&rZ[kbase]);
    float4 rz1 = *reinterpret_cast<const float4*>(&rZ[kbase + 4]);
    ushort4* vp = reinterpret_cast<ushort4*>(Vf + (size_t)i * 8);
    ushort4 a = vp[0], c = vp[1];
    vp[0] = make_ushort4(f2bf(bf2f(a.x) * rz0.x), f2bf(bf2f(a.y) * rz0.y),
                         f2bf(bf2f(a.z) * rz0.z), f2bf(bf2f(a.w) * rz0.w));
    vp[1] = make_ushort4(f2bf(bf2f(c.x) * rz1.x), f2bf(bf2f(c.y) * rz1.y),
                         f2bf(bf2f(c.z) * rz1.z), f2bf(bf2f(c.w) * rz1.w));
}

// ---------------- Kernel C: out = E^T' @ V' (r17 version, reverted) -------
// 64q x 256d block (4 waves: qh x dh), key-quarter split, grid 1024 = 4
// blocks/CU. E direct global->reg, order-pinned depth-2 rotation (eA/eB/eC),
// WAITV2 leaves exactly the 2 next-next E loads in flight. V 2-buffer LDS.
__global__ __launch_bounds__(256, 4) void pv_gemm(
    const u16* __restrict__ Ef, const u16* __restrict__ Vf, float* __restrict__ out)
{
    __shared__ __align__(16) u16 Vls[2][8192];    // 2 x 16KB (16 V frags: 32k x 256d)

    const int tid = threadIdx.x, blk = blockIdx.x;
    const int xcd = blk & 7, sub = blk >> 3;      // sub 0..127
    const int b  = xcd >> 1;
    const int ks = ((xcd & 1) << 1) | (sub & 1);  // key-quarter 0..3
    const int qt64 = sub >> 1;                    // 0..63 (64 q rows)
    const int w = tid >> 6, l = tid & 63, lr = l & 15, lg = l >> 4;
    const int qh = w & 1, dh = w >> 1;            // wave's q-half / d-half

    #define EADDR(it_, j_) \
        (Ef + e_base(b, ks * 32 + (it_), qt64 * 4 + qh * 2 + (j_)) + l * 8)

    // all 4 waves cooperatively stage the 16 V frags of k-chunk it_
    #define STAGE_V(it_, nb_) do { \
        const int kc_ = ks * 32 + (it_); \
        const size_t vb_ = ((size_t)(b * 64 + (kc_ >> 1))) * 16384 + (kc_ & 1) * 512; \
        _Pragma("unroll") \
        for (int f_ = 0; f_ < 4; ++f_) { \
            int dt_ = w * 4 + f_; \
            gll16(Vf + vb_ + (size_t)(dt_ * 2) * 512 + l * 8, &Vls[nb_][dt_ * 512]); \
        } \
    } while (0)

    #define COMPUTE(nb_, e0_, e1_) do { \
        __builtin_amdgcn_s_setprio(1); \
        _Pragma("unroll") \
        for (int dt = 0; dt < 8; ++dt) { \
            bf16x8 vfr = *reinterpret_cast<const bf16x8*>( \
                &Vls[nb_][(dh * 8 + dt) * 512 + l * 8]); \
            acc[0][dt] = __builtin_amdgcn_mfma_f32_16x16x32_bf16(e0_, vfr, acc[0][dt], 0, 0, 0); \
            acc[1][dt] = __builtin_amdgcn_mfma_f32_16x16x32_bf16(e1_, vfr, acc[1][dt], 0, 0, 0); \
        } \
        __builtin_amdgcn_s_setprio(0); \
    } while (0)

    // body: stage V(it+1) [fence] load E(it+2) [fence] compute(it), vmcnt(2)
    #define BODY(it_, eC0_, eC1_, eN0_, eN1_) do { \
        STAGE_V((it_) + 1, ((it_) + 1) & 1); \
        MEMFENCE; \
        eN0_ = *reinterpret_cast<const bf16x8*>(EADDR((it_) + 2, 0)); \
        eN1_ = *reinterpret_cast<const bf16x8*>(EADDR((it_) + 2, 1)); \
        MEMFENCE; \
        COMPUTE((it_) & 1, eC0_, eC1_); \
        WAITV2; \
        __builtin_amdgcn_s_barrier(); \
        MEMFENCE; \
    } while (0)

    f32x4 acc[2][8] = {};
    bf16x8 eA0, eA1, eB0, eB1, eC0, eC1;

    // prologue: eA=E(0) [fence] V(0)->buf0 [fence] eB=E(1);
    // vmcnt(2) retires eA+V0 (order pinned), leaves eB in flight.
    eA0 = *reinterpret_cast<const bf16x8*>(EADDR(0, 0));
    eA1 = *reinterpret_cast<const bf16x8*>(EADDR(0, 1));
    MEMFENCE;
    STAGE_V(0, 0);
    MEMFENCE;
    eB0 = *reinterpret_cast<const bf16x8*>(EADDR(1, 0));
    eB1 = *reinterpret_cast<const bf16x8*>(EADDR(1, 1));
    MEMFENCE;
    WAITV2;
    __builtin_amdgcn_s_barrier();
    MEMFENCE;

    #pragma unroll 1
    for (int base = 0; base < 30; base += 3) {
        BODY(base,     eA0, eA1, eC0, eC1);   // compute E(it),   load E(it+2)->eC
        BODY(base + 1, eB0, eB1, eA0, eA1);   // compute E(it+1), load E(it+3)->eA
        BODY(base + 2, eC0, eC1, eB0, eB1);   // compute E(it+2), load E(it+4)->eB
    }
    // it = 30 (uses eA; E(31)=eB already loaded at it=29): full drain
    STAGE_V(31, 1);
    COMPUTE(0, eA0, eA1);
    WAITV0;
    __builtin_amdgcn_s_barrier();
    MEMFENCE;
    // it = 31
    COMPUTE(1, eB0, eB1);

    // epilogue: C rows = q (lg*4+r), cols = d (lr); 4 contributions/element
    const int qg = b * S_LEN + qt64 * 64 + qh * 32;
    const int dg = dh * 128;
    #pragma unroll
    for (int qf = 0; qf < 2; ++qf) {
        #pragma unroll
        for (int dt = 0; dt < 8; ++dt) {
            #pragma unroll
            for (int r = 0; r < 4; ++r) {
                unsafeAtomicAdd(&out[(size_t)(qg + qf * 16 + lg * 4 + r) * D_DIM
                                     + dg + dt * 16 + lr],
                                acc[qf][dt][r]);
            }
        }
    }
    #undef EADDR
    #undef STAGE_V
    #undef COMPUTE
    #undef BODY
}

// ================= FALLBACK (round-11 fused attn_out) =====================
__global__ __launch_bounds__(512, 1) void attn_out_fb(
    const u16* __restrict__ Qf, const u16* __restrict__ Kf, const u16* __restrict__ Vf,
    const float* __restrict__ LZ, float* __restrict__ out)
{
    __shared__ __align__(16) u16 Kls[3][8192];
    __shared__ __align__(16) u16 Vls[4][8192];
    __shared__ __align__(16) u16 ps[8][2][1280];
    __shared__ __align__(16) float lzs[1024];

    const int tid = threadIdx.x, blk = blockIdx.x;
    const int xcd = blk & 7, sub = blk >> 3;
    const int b  = xcd >> 1;
    const int kq = ((xcd & 1) << 1) | (sub & 1);
    const int qtile = sub >> 1;
    const int w = tid >> 6, l = tid & 63, lr = l & 15, lg = l >> 4;
    const int q0 = qtile * 256 + w * 32;
    const int base_tk = b * 256;
    const int kt0 = kq * 32;

    bf16x8 qreg[2][8];
    #pragma unroll
    for (int qs = 0; qs < 2; ++qs) {
        const int tq = base_tk + ((q0 + qs * 16) >> 4);
        #pragma unroll
        for (int kk = 0; kk < 8; ++kk)
            qreg[qs][kk] = *reinterpret_cast<const bf16x8*>(Qf + fr_qk(tq, kk) + l * 8);
    }

    #define STAGE(kt_) do { \
        if (w < 4) { \
            const u16* g_ = Kf + ((size_t)(base_tk + (kt0 + (kt_)) * 2)) * 4096 + (w * 4) * 512 + l * 8; \
            u16* d_ = &Kls[(kt_) % 3][(w * 4) * 512]; \
            _Pragma("unroll") \
            for (int f_ = 0; f_ < 4; ++f_) gll16(g_ + f_ * 512, d_ + f_ * 512); \
        } else { \
            const int kta_ = kt0 + (kt_); \
            const size_t vb_ = ((size_t)(b * 64 + (kta_ >> 1))) * 16384 + (kta_ & 1) * 512; \
            const int dt0_ = (w - 4) * 4; \
            _Pragma("unroll") \
            for (int f_ = 0; f_ < 4; ++f_) \
                gll16(Vf + vb_ + (size_t)(dt0_ + f_) * 1024 + l * 8, &Vls[(kt_) % 4][(dt0_ + f_) * 512]); \
        } \
    } while (0)

    #define QK(kt_) do { \
        const u16* kb_ = &Kls[(kt_) % 3][0]; \
        __builtin_amdgcn_s_setprio(1); \
        _Pragma("unroll") \
        for (int kk = 0; kk < 8; ++kk) { \
            bf16x8 k0_ = *reinterpret_cast<const bf16x8*>(kb_ + kk * 512 + l * 8); \
            bf16x8 k1_ = *reinterpret_cast<const bf16x8*>(kb_ + (8 + kk) * 512 + l * 8); \
            sacc[0][0] = __builtin_amdgcn_mfma_f32_16x16x32_bf16(qreg[0][kk], k0_, sacc[0][0], 0, 0, 0); \
            sacc[0][1] = __builtin_amdgcn_mfma_f32_16x16x32_bf16(qreg[1][kk], k0_, sacc[0][1], 0, 0, 0); \
            sacc[1][0] = __builtin_amdgcn_mfma_f32_16x16x32_bf16(qreg[0][kk], k1_, sacc[1][0], 0, 0, 0); \
            sacc[1][1] = __builtin_amdgcn_mfma_f32_16x16x32_bf16(qreg[1][kk], k1_, sacc[1][1], 0, 0, 0); \
        } \
        __builtin_amdgcn_s_setprio(0); \
    } while (0)

    #define PV(j_) do { \
        const u16* vb_ = &Vls[(j_) % 4][0]; \
        const u16* pb_ = &ps[w][(j_) & 1][0]; \
        bf16x8 af0_ = *reinterpret_cast<const bf16x8*>(pb_ + lr * 40 + lg * 8); \
        bf16x8 af1_ = *reinterpret_cast<const bf16x8*>(pb_ + (16 + lr) * 40 + lg * 8); \
        __builtin_amdgcn_s_setprio(1); \
        _Pragma("unroll") \
        for (int dt = 0; dt < 16; ++dt) { \
            bf16x8 vf_ = *reinterpret_cast<const bf16x8*>(vb_ + dt * 512 + l * 8); \
            oacc[0][dt] = __builtin_amdgcn_mfma_f32_16x16x32_bf16(af0_, vf_, oacc[0][dt], 0, 0, 0); \
            oacc[1][dt] = __builtin_amdgcn_mfma_f32_16x16x32_bf16(af1_, vf_, oacc[1][dt], 0, 0, 0); \
        } \
        __builtin_amdgcn_s_setprio(0); \
    } while (0)

    #define SM(kt_) do { \
        u16* pw_ = &ps[w][(kt_) & 1][0]; \
        _Pragma("unroll") \
        for (int cf = 0; cf < 2; ++cf) { \
            float Lv_ = lzs[(kt_) * 32 + cf * 16 + lr]; \
            _Pragma("unroll") \
            for (int qs = 0; qs < 2; ++qs) \
                _Pragma("unroll") \
                for (int r = 0; r < 4; ++r) { \
                    float p_ = __expf(fmaf(sacc[cf][qs][r], SC, -Lv_)); \
                    pw_[(qs * 16 + lg * 4 + r) * 40 + cf * 16 + lr] = f2bf(p_); \
                } \
        } \
    } while (0)

    f32x4 oacc[2][16] = {};
    const float SC = 0.0625f;

    f32x4 lzv;
    if (tid < 256)
        lzv = *reinterpret_cast<const f32x4*>(LZ + b * S_LEN + kt0 * 32 + tid * 4);
    STAGE(0);
    STAGE(1);
    if (tid < 256)
        *reinterpret_cast<f32x4*>(&lzs[tid * 4]) = lzv;
    WAITLGKM0;
    WAITV4;
    __builtin_amdgcn_s_barrier();
    MEMFENCE;

    #pragma unroll 1
    for (int kt = 0; kt < 30; ++kt) {
        STAGE(kt + 2);
        f32x4 sacc[2][2] = {};
        QK(kt);
        if (kt > 0) PV(kt - 1);
        SM(kt);
        WAITV4;
        __builtin_amdgcn_s_barrier();
        MEMFENCE;
    }
    {
        f32x4 sacc[2][2] = {};
        QK(30); PV(29); SM(30);
        WAITV0;
        __builtin_amdgcn_s_barrier();
        MEMFENCE;
    }
    {
        f32x4 sacc[2][2] = {};
        QK(31); PV(30); SM(31); PV(31);
    }

    #pragma unroll
    for (int qs = 0; qs < 2; ++qs) {
        #pragma unroll
        for (int dt = 0; dt < 16; ++dt) {
            #pragma unroll
            for (int r = 0; r < 4; ++r) {
                int row = q0 + qs * 16 + lg * 4 + r;
                unsafeAtomicAdd(&out[((size_t)(b * S_LEN + row)) * D_DIM + dt * 16 + lr],
                                oacc[qs][dt][r]);
            }
        }
    }
    #undef STAGE
    #undef QK
    #undef PV
    #undef SM
}

// ---------------- launcher ------------------------------------------------
extern "C" void kernel_launch(void* const* d_in, const int* in_sizes, int n_in,
                              void* d_out, int out_size, void* d_ws, size_t ws_size,
                              hipStream_t stream) {
    const float* x  = (const float*)d_in[0];
    const float* Wq = (const float*)d_in[1];
    const float* bq = (const float*)d_in[2];
    const float* Wk = (const float*)d_in[3];
    const float* bk = (const float*)d_in[4];
    const float* Wv = (const float*)d_in[5];
    const float* bv = (const float*)d_in[6];
    float* out = (float*)d_out;

    u16* Qf = (u16*)d_ws;                              // 8 MB (fragment layout)
    u16* Kf = Qf + (size_t)NROW * D_DIM;               // 8 MB
    u16* Vf = Kf + (size_t)NROW * D_DIM;               // 8 MB
    u16* Wf = Vf + (size_t)NROW * D_DIM;               // 384 KB
    float* Zp = (float*)(Wf + 196608);                 // 512 KB (8 q-eighth partials)
    float* rZ = Zp + 8 * NROW;                         // 64 KB (rZ or LZ)
    u16* Ef = (u16*)(rZ + NROW);                       // 134.2 MB

    const size_t need = (size_t)((char*)Ef - (char*)d_ws) + (size_t)4 * 32768 * 512 * 2;

    hipMemsetAsync(out, 0, (size_t)NROW * D_DIM * sizeof(float), stream);
    wconv<<<96, 256, 0, stream>>>(Wq, Wk, Wv, Wf);
    qkv_proj<<<NROW / 32, 256, 0, stream>>>(x, Wf, bq, bk, bv, Qf, Kf, Vf);

    if (ws_size >= need) {
        score_exp<<<1024, 256, 0, stream>>>(Qf, Kf, Ef, Zp, 1);
        zrecip<<<NROW / 256, 256, 0, stream>>>(Zp, rZ);
        vscale<<<2048, 256, 0, stream>>>(Vf, rZ);
        pv_gemm<<<1024, 256, 0, stream>>>(Ef, Vf, out);
    } else {
        score_exp<<<1024, 256, 0, stream>>>(Qf, Kf, Qf /*unused*/, Zp, 0);
        zlog<<<NROW / 256, 256, 0, stream>>>(Zp, rZ);
        attn_out_fb<<<256, 512, 0, stream>>>(Qf, Kf, Vf, rZ, out);
    }
}